// Round 3
// baseline (90.494 us; speedup 1.0000x reference)
//
#include <hip/hip_runtime.h>

// 7x7 stride-2 VALID cross-correlation, X: 4096x4096 fp32, out: 2045x2045 fp32.
// out[i,j] = sum_{p,q} X[2i+p, 2j+q] * W[p,q]
//
// Block tile: 32 output rows x 64 output cols (grid 32x64), 256 threads.
// Stage the 69x136-float input footprint into LDS with DENSE global loads
// (lane-contiguous float4, 1KB per wave instruction), then compute from LDS.
// Per thread: 2x4 output micro-tile, 9 LDS rows x 16 floats.

static constexpr int H      = 4096;
static constexpr int OUT    = 2045;  // (4096-7)/2 + 1
static constexpr int PITCH4 = 34;    // float4s per LDS row (136 floats, no pad)
static constexpr int NIT    = 10;    // ceil(69*34 / 256) staging iterations

__global__ __launch_bounds__(256, 4) void conv7s2_kernel(
    const float* __restrict__ X,
    const float* __restrict__ W,
    float* __restrict__ out)
{
    __shared__ float lds[2560 * 4];   // 40 KiB (2346 real slots + pad)

    const int t  = threadIdx.x;
    const int bx = blockIdx.x, by = blockIdx.y;
    const int C0 = bx * 128;   // input col base (2*64 output cols)
    const int R0 = by * 64;    // input row base (2*32 output rows)

    // ---- stage: dense global -> reg -> LDS (linear layout) ----
    // slot l = lrow*34 + col4; lane-consecutive l => fully dense 16B/lane loads.
    float4 st[NIT];
#pragma unroll
    for (int it = 0; it < NIT; ++it) {
        const int l    = t + 256 * it;
        const int lrow = l / PITCH4;
        const int col4 = l - lrow * PITCH4;
        int grow = R0 + lrow;      if (grow > H - 1) grow = H - 1;  // clamp: garbage
        int gcol = C0 + 4 * col4;  if (gcol > H - 4) gcol = H - 4;  // feeds only
        st[it] = *reinterpret_cast<const float4*>(X + (size_t)grow * H + gcol);
    }
#pragma unroll
    for (int it = 0; it < NIT; ++it) {
        const int l = t + 256 * it;
        *reinterpret_cast<float4*>(&lds[l * 4]) = st[it];   // conflict-free: lane-linear
    }
    __syncthreads();

    // Uniform-address weight loads -> SGPRs.
    float w[49];
#pragma unroll
    for (int i = 0; i < 49; ++i) w[i] = W[i];

    const int tx   = t & 15;    // 16 threads x 4 cols = 64 cols
    const int ty   = t >> 4;    // 16 threads x 2 rows = 32 rows
    const int flip = ty & 1;    // bank-spread trick: lanes of opposite ty parity
                                // read their 4 chunks in swapped order, giving
                                // 8 distinct 4-bank groups x 8 lanes (b128 floor).

    float acc0[4] = {0.f, 0.f, 0.f, 0.f};
    float acc1[4] = {0.f, 0.f, 0.f, 0.f};

#pragma unroll
    for (int r = 0; r < 9; ++r) {
        const int lrow = 4 * ty + r;            // input tile row
        const int base = lrow * 136 + tx * 8;   // float index
        float rv[16];
#pragma unroll
        for (int i = 0; i < 4; ++i) {
            const int kk = i ^ flip;
            const float4 v = *reinterpret_cast<const float4*>(&lds[base + 4 * kk]);
            rv[4 * kk + 0] = v.x;
            rv[4 * kk + 1] = v.y;
            rv[4 * kk + 2] = v.z;
            rv[4 * kk + 3] = v.w;
        }
#pragma unroll
        for (int q = 0; q < 7; ++q) {
#pragma unroll
            for (int j = 0; j < 4; ++j) {
                const float cv = rv[2 * j + q];
                if (r <= 6) acc0[j] = fmaf(cv, w[r * 7 + q],       acc0[j]);
                if (r >= 2) acc1[j] = fmaf(cv, w[(r - 2) * 7 + q], acc1[j]);
            }
        }
    }

    const int x0 = bx * 64 + tx * 4;
    const int y0 = by * 32 + ty * 2;
#pragma unroll
    for (int j = 0; j < 4; ++j) {
        const int x = x0 + j;
        if (x < OUT) {
            if (y0     < OUT) out[(size_t)y0       * OUT + x] = acc0[j];
            if (y0 + 1 < OUT) out[(size_t)(y0 + 1) * OUT + x] = acc1[j];
        }
    }
}

extern "C" void kernel_launch(void* const* d_in, const int* in_sizes, int n_in,
                              void* d_out, int out_size, void* d_ws, size_t ws_size,
                              hipStream_t stream) {
    const float* X = (const float*)d_in[0];
    const float* W = (const float*)d_in[1];
    float* out = (float*)d_out;

    dim3 grid(32, 64);   // ceil(2045/64) x ceil(2045/32)
    conv7s2_kernel<<<grid, 256, 0, stream>>>(X, W, out);
}

// Round 4
// 23.858 us; speedup vs baseline: 3.7931x; 3.7931x over previous
//
#include <hip/hip_runtime.h>

// 7x7 stride-2 VALID cross-correlation, X: 4096x4096 fp32, out: 2045x2045 fp32.
// out[i,j] = sum_{p,q} X[2i+p, 2j+q] * W[p,q]
//
// Block tile: 32 output rows x 64 output cols (grid 32x64), 256 threads.
// Stage the 69x136-float input footprint into LDS with dense global loads,
// XOR-swizzled *in the address only* (all register indices compile-time).
// Per thread: 2x4 output micro-tile, 9 LDS rows x 4 ds_read_b128.

static constexpr int H     = 4096;
static constexpr int OUT   = 2045;  // (4096-7)/2 + 1
static constexpr int P4    = 36;    // float4 slots per LDS row (XOR-safe pad)
static constexpr int NIT   = 10;    // ceil(69*36 / 256) = 10 staging iters
static constexpr int SLOTS = 2560;  // NIT * 256

__global__ __launch_bounds__(256, 4) void conv7s2_kernel(
    const float* __restrict__ X,
    const float* __restrict__ W,
    float* __restrict__ out)
{
    __shared__ float4 lds4[SLOTS];   // 40 KiB -> 4 blocks/CU

    const int t  = threadIdx.x;
    const int bx = blockIdx.x, by = blockIdx.y;
    const int C0 = bx * 128;   // input col base
    const int R0 = by * 64;    // input row base

    // ---- stage: global -> reg -> LDS ----
    // Slot u of row lrow holds logical chunk (u ^ s), s = (lrow>>2)&3.
    // => global source col is swizzled; LDS write is lane-linear (no conflict).
    float4 st[NIT];
#pragma unroll
    for (int it = 0; it < NIT; ++it) {
        const int l     = t + 256 * it;
        const int lrow  = l / P4;
        const int col4  = l - lrow * P4;
        const int s     = (lrow >> 2) & 3;
        const int chunk = col4 ^ s;           // logical chunk this slot holds
        int grow = R0 + lrow;       if (grow > H - 1) grow = H - 1;  // garbage only
        int gcol = C0 + 4 * chunk;  if (gcol > H - 4) gcol = H - 4;  // feeds guarded outputs
        st[it] = *reinterpret_cast<const float4*>(X + (size_t)grow * H + gcol);
    }
#pragma unroll
    for (int it = 0; it < NIT; ++it) {
        lds4[t + 256 * it] = st[it];          // lane-linear: conflict-free
    }
    __syncthreads();

    // Uniform-address weight loads -> SGPRs.
    float w[49];
#pragma unroll
    for (int i = 0; i < 49; ++i) w[i] = W[i];

    const int tx = t & 15;    // 16 threads x 4 output cols
    const int ty = t >> 4;    // 16 threads x 2 output rows
    const int c2 = 2 * tx;    // first logical chunk this lane needs

    float acc0[4] = {0.f, 0.f, 0.f, 0.f};
    float acc1[4] = {0.f, 0.f, 0.f, 0.f};

#pragma unroll
    for (int r = 0; r < 9; ++r) {
        const int lrow    = 4 * ty + r;
        const int rowbase = lrow * P4;
        const int s       = (lrow >> 2) & 3;

        // Static register indices; swizzle lives in the LDS address only.
        // Bank math: 8 distinct 4-bank starts x 8 lanes = b128 floor.
        float rv[16];
#pragma unroll
        for (int i = 0; i < 4; ++i) {
            const float4 v = lds4[rowbase + ((c2 + i) ^ s)];
            rv[4 * i + 0] = v.x;
            rv[4 * i + 1] = v.y;
            rv[4 * i + 2] = v.z;
            rv[4 * i + 3] = v.w;
        }

#pragma unroll
        for (int q = 0; q < 7; ++q) {
#pragma unroll
            for (int j = 0; j < 4; ++j) {
                const float cv = rv[2 * j + q];
                if (r <= 6) acc0[j] = fmaf(cv, w[r * 7 + q],       acc0[j]);
                if (r >= 2) acc1[j] = fmaf(cv, w[(r - 2) * 7 + q], acc1[j]);
            }
        }
    }

    const int x0 = bx * 64 + tx * 4;
    const int y0 = by * 32 + ty * 2;
#pragma unroll
    for (int j = 0; j < 4; ++j) {
        const int x = x0 + j;
        if (x < OUT) {
            if (y0     < OUT) out[(size_t)y0       * OUT + x] = acc0[j];
            if (y0 + 1 < OUT) out[(size_t)(y0 + 1) * OUT + x] = acc1[j];
        }
    }
}

extern "C" void kernel_launch(void* const* d_in, const int* in_sizes, int n_in,
                              void* d_out, int out_size, void* d_ws, size_t ws_size,
                              hipStream_t stream) {
    const float* X = (const float*)d_in[0];
    const float* W = (const float*)d_in[1];
    float* out = (float*)d_out;

    dim3 grid(32, 64);   // ceil(2045/64) x ceil(2045/32)
    conv7s2_kernel<<<grid, 256, 0, stream>>>(X, W, out);
}